// Round 1
// baseline (47.963 us; speedup 1.0000x reference)
//
#include <hip/hip_runtime.h>
#include <math.h>

#define A_N 200000
#define B_N 8
#define M_N 32
#define THREADS 256
#define APT 4                       // anchors per thread
#define APB (THREADS * APT)         // anchors per block = 1024
#define BPI ((A_N + APB - 1) / APB) // blocks per image = 196

__device__ __forceinline__ float sl1(float d) {
    d = fabsf(d);
    return (d <= (1.0f / 9.0f)) ? (4.5f * d * d) : (d - (1.0f / 18.0f));
}

__global__ __launch_bounds__(THREADS)
void focal_main(const float* __restrict__ cls,
                const float4* __restrict__ reg,
                const float4* __restrict__ anchors,
                const float* __restrict__ ann,
                float* __restrict__ partials)
{
    const int blk = blockIdx.x;
    const int b   = blockIdx.y;
    const int tid = threadIdx.x;

    __shared__ float4 sbox[M_N];
    __shared__ float  sarea[M_N];
    __shared__ float  wred[THREADS / 64][3];

    if (tid < M_N) {
        const float* p = ann + (size_t)(b * M_N + tid) * 5;
        float x1 = p[0], y1 = p[1], x2 = p[2], y2 = p[3];
        sbox[tid]  = make_float4(x1, y1, x2, y2);
        sarea[tid] = (x2 - x1) * (y2 - y1);
    }
    __syncthreads();

    const int abase = blk * APB + tid;

    float ax1[APT], ay1[APT], ax2[APT], ay2[APT], areaA[APT];
    float bi[APT], bu[APT];   // best inter / best ua (clipped)
    int   bj[APT];
    #pragma unroll
    for (int k = 0; k < APT; k++) {
        int a  = abase + k * THREADS;
        int al = (a < A_N) ? a : (A_N - 1);
        float4 v = anchors[al];
        ax1[k] = v.x; ay1[k] = v.y; ax2[k] = v.z; ay2[k] = v.w;
        areaA[k] = (v.z - v.x) * (v.w - v.y);
        bi[k] = -1.0f; bu[k] = 1.0f; bj[k] = 0;
    }

    for (int j = 0; j < M_N; j++) {
        float4 bb = sbox[j];
        float  ab = sarea[j];
        #pragma unroll
        for (int k = 0; k < APT; k++) {
            float iw = fminf(ax2[k], bb.z) - fmaxf(ax1[k], bb.x);
            float ih = fminf(ay2[k], bb.w) - fmaxf(ay1[k], bb.y);
            iw = fmaxf(iw, 0.0f);
            ih = fmaxf(ih, 0.0f);
            float inter = iw * ih;
            float ua = fmaxf(areaA[k] + ab - inter, 1e-8f);
            // iou_j > iou_best  <=>  inter_j * ua_best > inter_best * ua_j  (ua > 0)
            if (inter * bu[k] > bi[k] * ua) { bi[k] = inter; bu[k] = ua; bj[k] = j; }
        }
    }

    float cls_sum = 0.0f, reg_sum = 0.0f, npos = 0.0f;
    #pragma unroll
    for (int k = 0; k < APT; k++) {
        int a = abase + k * THREADS;
        if (a >= A_N) continue;
        float iou = bi[k] / bu[k];
        float p = cls[((size_t)b * A_N + a) * 4];   // only channel 0 contributes
        p = fminf(fmaxf(p, 1e-5f), 1.0f - 1e-5f);
        if (iou >= 0.5f) {
            float omp = 1.0f - p;
            cls_sum += 0.25f * omp * omp * (-__logf(p));
            npos += 1.0f;
            float4 bb = sbox[bj[k]];
            float aw = ax2[k] - ax1[k], ah = ay2[k] - ay1[k];
            float acx = ax1[k] + 0.5f * aw, acy = ay1[k] + 0.5f * ah;
            float gwr = bb.z - bb.x, ghr = bb.w - bb.y;
            float gcx = bb.x + 0.5f * gwr, gcy = bb.y + 0.5f * ghr;
            float gw = fmaxf(gwr, 1.0f), gh = fmaxf(ghr, 1.0f);
            float4 r = reg[(size_t)b * A_N + a];
            float rt0 = ((gcx - acx) / aw) / 0.1f;
            float rt1 = ((gcy - acy) / ah) / 0.1f;
            float rt2 = __logf(gw / aw) / 0.2f;
            float rt3 = __logf(gh / ah) / 0.2f;
            reg_sum += sl1(rt0 - r.x) + sl1(rt1 - r.y) + sl1(rt2 - r.z) + sl1(rt3 - r.w);
        } else if (iou < 0.4f) {
            cls_sum += 0.75f * p * p * (-__logf(1.0f - p));
        }
    }

    // wave reduce (64 lanes)
    #pragma unroll
    for (int off = 32; off > 0; off >>= 1) {
        cls_sum += __shfl_down(cls_sum, off);
        reg_sum += __shfl_down(reg_sum, off);
        npos    += __shfl_down(npos, off);
    }
    int wid = tid >> 6;
    if ((tid & 63) == 0) {
        wred[wid][0] = cls_sum; wred[wid][1] = reg_sum; wred[wid][2] = npos;
    }
    __syncthreads();
    if (tid == 0) {
        float c = 0.0f, r = 0.0f, n = 0.0f;
        #pragma unroll
        for (int w = 0; w < THREADS / 64; w++) {
            c += wred[w][0]; r += wred[w][1]; n += wred[w][2];
        }
        float* dst = partials + (size_t)(b * BPI + blk) * 3;
        dst[0] = c; dst[1] = r; dst[2] = n;
    }
}

__global__ void focal_reduce(const float* __restrict__ partials, float* __restrict__ out)
{
    int tid = threadIdx.x;  // 64 threads, 1 wave
    float cacc = 0.0f, racc = 0.0f;
    for (int b = 0; b < B_N; b++) {
        float cs = 0.0f, rs = 0.0f, np = 0.0f;
        for (int i = tid; i < BPI; i += 64) {
            const float* p = partials + (size_t)(b * BPI + i) * 3;
            cs += p[0]; rs += p[1]; np += p[2];
        }
        #pragma unroll
        for (int off = 32; off > 0; off >>= 1) {
            cs += __shfl_down(cs, off);
            rs += __shfl_down(rs, off);
            np += __shfl_down(np, off);
        }
        if (tid == 0) {
            cacc += cs / fmaxf(np, 1.0f);
            racc += (np > 0.0f) ? (rs / (4.0f * np)) : 0.0f;
        }
    }
    if (tid == 0) {
        out[0] = cacc / (float)B_N;
        out[1] = racc / (float)B_N;
    }
}

extern "C" void kernel_launch(void* const* d_in, const int* in_sizes, int n_in,
                              void* d_out, int out_size, void* d_ws, size_t ws_size,
                              hipStream_t stream)
{
    const float*  cls     = (const float*)d_in[0];
    const float4* reg     = (const float4*)d_in[1];
    const float4* anchors = (const float4*)d_in[2];
    const float*  ann     = (const float*)d_in[3];
    float* partials = (float*)d_ws;   // [B_N][BPI][3] floats, every slot written each launch
    float* out      = (float*)d_out;

    dim3 grid(BPI, B_N);
    focal_main<<<grid, THREADS, 0, stream>>>(cls, reg, anchors, ann, partials);
    focal_reduce<<<1, 64, 0, stream>>>(partials, out);
}